// Round 1
// baseline (13535.072 us; speedup 1.0000x reference)
//
#include <hip/hip_runtime.h>
#include <hip/hip_bf16.h>
#include <hip/hip_cooperative_groups.h>

namespace cg = cooperative_groups;

// Problem constants
#define BB   128
#define SS   512
#define IND  512
#define HID  1024

// LDS row pads (+8 shorts = +16B) -> even bank distribution for ds_read_b128
#define WHH_LD (HID + 8)   // 1032 shorts/row
#define WIH_LD (IND + 8)   // 520 shorts/row

typedef __attribute__((ext_vector_type(8))) short s8v;   // 8 x bf16 (bit pattern)
typedef __attribute__((ext_vector_type(4))) float f4v;   // MFMA accumulator

__device__ __forceinline__ short f2bf(float f) {
    union { float f; unsigned u; } v; v.f = f;
    unsigned u = v.u + 0x7FFFu + ((v.u >> 16) & 1u);     // RNE
    return (short)(u >> 16);
}
__device__ __forceinline__ float bf2f(short s) {
    union { unsigned u; float f; } v;
    v.u = ((unsigned)(unsigned short)s) << 16;
    return v.f;
}

// Persistent cooperative GRU kernel.
// Grid: 128 blocks = 2 row-halves (mi) x 64 column-groups (jg), 256 threads (4 waves).
// Block (mi, jg): batch rows [mi*64, mi*64+64), hidden cols [jg*16, jg*16+16).
// Wave w owns the 16-row M-tile [mi*64 + w*16, +16).
// LDS holds bf16 slices: w_hh rows {g*HID + jg*16+jj} (48x1024) and w_ih (48x512),
// resident for all 512 steps.
__global__ void __launch_bounds__(256, 1)
gru_persistent(const float* __restrict__ X,     // [B,S,IND]
               const float* __restrict__ Wih,   // [3H, IND]
               const float* __restrict__ Whh,   // [3H, HID]
               const float* __restrict__ bih,   // [3H]
               const float* __restrict__ bhh,   // [3H]
               float* __restrict__ out,         // [B,S,H] ++ [B,H]
               short* __restrict__ hbuf)        // ws: 2 x B*HID bf16 (ping-pong)
{
    __shared__ __align__(16) short whh_lds[48 * WHH_LD]; //  99072 B
    __shared__ __align__(16) short wih_lds[48 * WIH_LD]; //  49920 B

    const int tid  = threadIdx.x;
    const int wave = tid >> 6;
    const int lane = tid & 63;
    const int blk  = blockIdx.x;
    const int mi   = blk >> 6;      // 0..1 row half
    const int jg   = blk & 63;      // column group

    // ---- stage weight slices to LDS as bf16 (once; resident all 512 steps) ----
    for (int idx = tid; idx < 48 * (HID / 4); idx += 256) {
        int s  = idx / (HID / 4);
        int k4 = idx % (HID / 4);
        int grow = (s >> 4) * HID + jg * 16 + (s & 15);    // global w_hh row
        float4 v = *(const float4*)(Whh + (size_t)grow * HID + k4 * 4);
        short* d = &whh_lds[s * WHH_LD + k4 * 4];
        d[0] = f2bf(v.x); d[1] = f2bf(v.y); d[2] = f2bf(v.z); d[3] = f2bf(v.w);
    }
    for (int idx = tid; idx < 48 * (IND / 4); idx += 256) {
        int s  = idx / (IND / 4);
        int k4 = idx % (IND / 4);
        int grow = (s >> 4) * HID + jg * 16 + (s & 15);    // global w_ih row
        float4 v = *(const float4*)(Wih + (size_t)grow * IND + k4 * 4);
        short* d = &wih_lds[s * WIH_LD + k4 * 4];
        d[0] = f2bf(v.x); d[1] = f2bf(v.y); d[2] = f2bf(v.z); d[3] = f2bf(v.w);
    }

    // per-lane constants: frag row/col index n = lane&15, k-group kg = lane>>4
    const int n  = lane & 15;
    const int kg = lane >> 4;
    const int j  = jg * 16 + n;                 // hidden column this lane outputs
    const float bir = bih[j], biz = bih[HID + j], bin_ = bih[2 * HID + j];
    const float bhr = bhh[j], bhz = bhh[HID + j], bhn  = bhh[2 * HID + j];

    const int rowbase = mi * 64 + wave * 16;    // this wave's 16 batch rows

    __syncthreads();

    cg::grid_group grid = cg::this_grid();

    for (int t = 0; t < SS; ++t) {
        f4v acc_r  = {0.f, 0.f, 0.f, 0.f};
        f4v acc_z  = {0.f, 0.f, 0.f, 0.f};
        f4v acc_in = {0.f, 0.f, 0.f, 0.f};
        f4v acc_hn = {0.f, 0.f, 0.f, 0.f};

        // ---- gi contribution: X[:,t,:] @ Wih_slice^T  (K = 512) ----
        {
            const float* xrow = X + ((size_t)(rowbase + n) * SS + t) * IND;
            #pragma unroll 4
            for (int kk = 0; kk < IND / 32; ++kk) {
                const int k0 = kk * 32 + kg * 8;
                const float4* px = (const float4*)(xrow + k0);
                float4 x0 = px[0], x1 = px[1];
                s8v a;
                a[0] = f2bf(x0.x); a[1] = f2bf(x0.y); a[2] = f2bf(x0.z); a[3] = f2bf(x0.w);
                a[4] = f2bf(x1.x); a[5] = f2bf(x1.y); a[6] = f2bf(x1.z); a[7] = f2bf(x1.w);
                s8v br = *(const s8v*)&wih_lds[(0 * 16 + n) * WIH_LD + k0];
                s8v bz = *(const s8v*)&wih_lds[(1 * 16 + n) * WIH_LD + k0];
                s8v bn = *(const s8v*)&wih_lds[(2 * 16 + n) * WIH_LD + k0];
                acc_r  = __builtin_amdgcn_mfma_f32_16x16x32_bf16(a, br, acc_r,  0, 0, 0);
                acc_z  = __builtin_amdgcn_mfma_f32_16x16x32_bf16(a, bz, acc_z,  0, 0, 0);
                acc_in = __builtin_amdgcn_mfma_f32_16x16x32_bf16(a, bn, acc_in, 0, 0, 0);
            }
        }

        // ---- gh contribution: h_{t-1} @ Whh_slice^T  (K = 1024), skip at t=0 (h0=0) ----
        if (t > 0) {
            const short* hprev = hbuf + ((t - 1) & 1) * (BB * HID)
                               + (size_t)(rowbase + n) * HID;
            #pragma unroll 4
            for (int kk = 0; kk < HID / 32; ++kk) {
                const int k0 = kk * 32 + kg * 8;
                s8v a  = *(const s8v*)(hprev + k0);
                s8v br = *(const s8v*)&whh_lds[(0 * 16 + n) * WHH_LD + k0];
                s8v bz = *(const s8v*)&whh_lds[(1 * 16 + n) * WHH_LD + k0];
                s8v bn = *(const s8v*)&whh_lds[(2 * 16 + n) * WHH_LD + k0];
                acc_r  = __builtin_amdgcn_mfma_f32_16x16x32_bf16(a, br, acc_r,  0, 0, 0);
                acc_z  = __builtin_amdgcn_mfma_f32_16x16x32_bf16(a, bz, acc_z,  0, 0, 0);
                acc_hn = __builtin_amdgcn_mfma_f32_16x16x32_bf16(a, bn, acc_hn, 0, 0, 0);
            }
        }

        // ---- gates + state update.  D layout: row m=(lane>>4)*4+r, col n=lane&15 ----
        {
            const short* hprev_rd = hbuf + ((t - 1) & 1) * (BB * HID);
            short*       hcur     = hbuf + (t & 1) * (BB * HID);
            #pragma unroll
            for (int r = 0; r < 4; ++r) {
                const int b = rowbase + kg * 4 + r;
                float gr = acc_r[r] + bir + bhr;
                float gz = acc_z[r] + biz + bhz;
                float rr = 1.f / (1.f + __expf(-gr));
                float zz = 1.f / (1.f + __expf(-gz));
                float hn = acc_hn[r] + bhn;                 // t=0: acc_hn=0 -> bhn
                float na = acc_in[r] + bin_ + rr * hn;
                float e2 = __expf(2.f * na);                // tanh(na)
                float nn = (e2 - 1.f) / (e2 + 1.f);
                float hp = (t == 0) ? 0.f : bf2f(hprev_rd[(size_t)b * HID + j]);
                float hnew = (1.f - zz) * nn + zz * hp;
                hcur[(size_t)b * HID + j] = f2bf(hnew);
                out[(size_t)b * (SS * HID) + (size_t)t * HID + j] = hnew;
                if (t == SS - 1)
                    out[(size_t)BB * SS * HID + (size_t)b * HID + j] = hnew;
            }
        }

        grid.sync();   // h_t visible (device-scope release/acquire) before step t+1
    }
}

extern "C" void kernel_launch(void* const* d_in, const int* in_sizes, int n_in,
                              void* d_out, int out_size, void* d_ws, size_t ws_size,
                              hipStream_t stream) {
    const float* X   = (const float*)d_in[0];
    const float* Wih = (const float*)d_in[1];
    const float* Whh = (const float*)d_in[2];
    const float* bih = (const float*)d_in[3];
    const float* bhh = (const float*)d_in[4];
    float* out  = (float*)d_out;
    short* hbuf = (short*)d_ws;   // needs 2*128*1024*2 = 512 KB

    void* args[] = { (void*)&X, (void*)&Wih, (void*)&Whh, (void*)&bih,
                     (void*)&bhh, (void*)&out, (void*)&hbuf };
    hipLaunchCooperativeKernel((const void*)gru_persistent,
                               dim3(128), dim3(256), args, 0, stream);
}

// Round 2
// 6796.272 us; speedup vs baseline: 1.9915x; 1.9915x over previous
//
#include <hip/hip_runtime.h>
#include <hip/hip_bf16.h>

// Problem constants
#define BB   128
#define SS   512
#define IND  512
#define HID  1024
#define NBLK 256   // 4 row-quarters (mi) x 64 column-groups (jg)

#define WHH_LD (HID + 8)   // LDS row pad
#define WIH_LD (IND + 8)

typedef __attribute__((ext_vector_type(8))) short s8v;   // 8 x bf16
typedef __attribute__((ext_vector_type(4))) float f4v;   // MFMA accumulator
typedef unsigned long long u64;
typedef unsigned int u32;

__device__ __forceinline__ short f2bf(float f) {
    union { float f; u32 u; } v; v.f = f;
    u32 u = v.u + 0x7FFFu + ((v.u >> 16) & 1u);          // RNE
    return (short)(u >> 16);
}

// h ping-pong layout (bf16, per buffer 256 KB):
//   [wg=8][kk=32][kg=4][row 16][8 shorts]
// Reader wave (row-group wg) at iter kk: lane (n,kg) reads 16B at
// lane*16 -> perfectly lane-contiguous 1KB per instruction.
// Element (b, j) lives at byte:
//   (b/16)*32768 + (j>>5)*1024 + ((j>>3)&3)*256 + (b%16)*16 + (j&7)*2

__global__ void __launch_bounds__(128, 1)
gru_persistent(const float* __restrict__ X,     // [B,S,IND]
               const float* __restrict__ Wih,   // [3H, IND]
               const float* __restrict__ Whh,   // [3H, HID]
               const float* __restrict__ bih,   // [3H]
               const float* __restrict__ bhh,   // [3H]
               float* __restrict__ out,         // [B,S,H] ++ [B,H]
               short* __restrict__ bufA,        // ws scratch (even t)
               short* __restrict__ bufB,        // d_out tail region (odd t)
               u64*   __restrict__ ctr)         // barrier counter (zeroed each launch)
{
    __shared__ __align__(16) short whh_lds[48 * WHH_LD];
    __shared__ __align__(16) short wih_lds[48 * WIH_LD];

    const int tid  = threadIdx.x;
    const int wave = tid >> 6;      // 0..1
    const int lane = tid & 63;
    const int blk  = blockIdx.x;
    const int mi   = blk >> 6;      // 0..3 row quarter
    const int jg   = blk & 63;      // column group

    // ---- stage weight slices to LDS as bf16 (once) ----
    for (int idx = tid; idx < 48 * (HID / 4); idx += 128) {
        int s = idx / (HID / 4), k4 = idx % (HID / 4);
        int grow = (s >> 4) * HID + jg * 16 + (s & 15);
        float4 v = *(const float4*)(Whh + (size_t)grow * HID + k4 * 4);
        short* d = &whh_lds[s * WHH_LD + k4 * 4];
        d[0] = f2bf(v.x); d[1] = f2bf(v.y); d[2] = f2bf(v.z); d[3] = f2bf(v.w);
    }
    for (int idx = tid; idx < 48 * (IND / 4); idx += 128) {
        int s = idx / (IND / 4), k4 = idx % (IND / 4);
        int grow = (s >> 4) * HID + jg * 16 + (s & 15);
        float4 v = *(const float4*)(Wih + (size_t)grow * IND + k4 * 4);
        short* d = &wih_lds[s * WIH_LD + k4 * 4];
        d[0] = f2bf(v.x); d[1] = f2bf(v.y); d[2] = f2bf(v.z); d[3] = f2bf(v.w);
    }

    const int n  = lane & 15;
    const int kg = lane >> 4;
    const int j  = jg * 16 + n;
    const float bir = bih[j], biz = bih[HID + j], bin_ = bih[2 * HID + j];
    const float bhr = bhh[j], bhz = bhh[HID + j], bhn  = bhh[2 * HID + j];

    const int rowbase = mi * 32 + wave * 16;
    const int wg      = mi * 2 + wave;          // row-group = rowbase/16

    // writer byte offset (even lanes store packed u32 covering cols j, j+1)
    const int wkk = j >> 5, wkg = (j >> 3) & 3;
    const u32 wbyte = (u32)wg * 32768u + (u32)wkk * 1024u + (u32)wkg * 256u
                    + (u32)kg * 64u + ((u32)(n & 7) << 1);

    float hkeep[4] = {0.f, 0.f, 0.f, 0.f};      // this lane's own h elements

    __syncthreads();

    for (int t = 0; t < SS; ++t) {
        f4v acc_r  = {0.f,0.f,0.f,0.f};
        f4v acc_z  = {0.f,0.f,0.f,0.f};
        f4v acc_in = {0.f,0.f,0.f,0.f};
        f4v acc_hn = {0.f,0.f,0.f,0.f};

        // ---- gi: X[:,t,:] @ Wih_slice^T (K=512), normal cached loads ----
        {
            const float* xrow = X + ((size_t)(rowbase + n) * SS + t) * IND;
            #pragma unroll 4
            for (int kk = 0; kk < IND / 32; ++kk) {
                const int k0 = kk * 32 + kg * 8;
                const float4* px = (const float4*)(xrow + k0);
                float4 x0 = px[0], x1 = px[1];
                s8v a;
                a[0]=f2bf(x0.x); a[1]=f2bf(x0.y); a[2]=f2bf(x0.z); a[3]=f2bf(x0.w);
                a[4]=f2bf(x1.x); a[5]=f2bf(x1.y); a[6]=f2bf(x1.z); a[7]=f2bf(x1.w);
                s8v br = *(const s8v*)&wih_lds[(0 * 16 + n) * WIH_LD + k0];
                s8v bz = *(const s8v*)&wih_lds[(1 * 16 + n) * WIH_LD + k0];
                s8v bn = *(const s8v*)&wih_lds[(2 * 16 + n) * WIH_LD + k0];
                acc_r  = __builtin_amdgcn_mfma_f32_16x16x32_bf16(a, br, acc_r,  0,0,0);
                acc_z  = __builtin_amdgcn_mfma_f32_16x16x32_bf16(a, bz, acc_z,  0,0,0);
                acc_in = __builtin_amdgcn_mfma_f32_16x16x32_bf16(a, bn, acc_in, 0,0,0);
            }
        }

        // ---- gh: h_{t-1} @ Whh_slice^T (K=1024) via LLC-coherent loads ----
        if (t > 0) {
            const short* hr = (t & 1) ? bufA : bufB;          // h_{t-1}
            const u64* hb = (const u64*)hr + (size_t)wg * 4096 + lane * 2;
            s8v areg[32];
            #pragma unroll
            for (int kk = 0; kk < 32; ++kk) {
                u64 lo = __hip_atomic_load(hb + kk * 128,
                                           __ATOMIC_RELAXED, __HIP_MEMORY_SCOPE_AGENT);
                u64 hi = __hip_atomic_load(hb + kk * 128 + 1,
                                           __ATOMIC_RELAXED, __HIP_MEMORY_SCOPE_AGENT);
                union { u64 q[2]; s8v v; } u; u.q[0] = lo; u.q[1] = hi;
                areg[kk] = u.v;
            }
            #pragma unroll
            for (int kk = 0; kk < 32; ++kk) {
                const int k0 = kk * 32 + kg * 8;
                s8v br = *(const s8v*)&whh_lds[(0 * 16 + n) * WHH_LD + k0];
                s8v bz = *(const s8v*)&whh_lds[(1 * 16 + n) * WHH_LD + k0];
                s8v bn = *(const s8v*)&whh_lds[(2 * 16 + n) * WHH_LD + k0];
                acc_r  = __builtin_amdgcn_mfma_f32_16x16x32_bf16(areg[kk], br, acc_r,  0,0,0);
                acc_z  = __builtin_amdgcn_mfma_f32_16x16x32_bf16(areg[kk], bz, acc_z,  0,0,0);
                acc_hn = __builtin_amdgcn_mfma_f32_16x16x32_bf16(areg[kk], bn, acc_hn, 0,0,0);
            }
        }

        // ---- gates + state update; h kept in regs ----
        short* hw = (t & 1) ? bufB : bufA;                    // h_t
        u32 packv[4];
        #pragma unroll
        for (int r = 0; r < 4; ++r) {
            const int b = rowbase + kg * 4 + r;
            float gr = acc_r[r] + bir + bhr;
            float gz = acc_z[r] + biz + bhz;
            float rr = 1.f / (1.f + __expf(-gr));
            float zz = 1.f / (1.f + __expf(-gz));
            float hn = acc_hn[r] + bhn;                       // t=0: == bhn
            float na = acc_in[r] + bin_ + rr * hn;
            float e2 = __expf(2.f * na);
            float nn = (e2 - 1.f) / (e2 + 1.f);
            float hnew = (1.f - zz) * nn + zz * hkeep[r];
            hkeep[r] = hnew;
            out[(size_t)b * (SS * HID) + (size_t)t * HID + j] = hnew;
            if (t == SS - 1)
                out[(size_t)BB * SS * HID + (size_t)b * HID + j] = hnew;
            u32 hb16  = (u32)(unsigned short)f2bf(hnew);
            u32 other = (u32)__shfl_xor((int)hb16, 1);
            packv[r] = hb16 | (other << 16);                  // cols j (lo), j+1 (hi)
        }

        if (t < SS - 1) {
            if (!(n & 1)) {
                #pragma unroll
                for (int r = 0; r < 4; ++r)
                    __hip_atomic_store((u32*)((char*)hw + wbyte + r * 16), packv[r],
                                       __ATOMIC_RELAXED, __HIP_MEMORY_SCOPE_AGENT);
            }
            // ---- lightweight grid barrier: no L2 writeback/invalidate.
            // __syncthreads drains vmcnt(0) -> all sc-coherent stores are at LLC
            // before the leader's arrive-add; readers use LLC-coherent loads.
            __syncthreads();
            if (tid == 0) {
                __hip_atomic_fetch_add(ctr, 1ull,
                                       __ATOMIC_RELAXED, __HIP_MEMORY_SCOPE_AGENT);
                const u64 target = (u64)NBLK * (u64)(t + 1);
                while (__hip_atomic_load(ctr, __ATOMIC_RELAXED,
                                         __HIP_MEMORY_SCOPE_AGENT) < target)
                    __builtin_amdgcn_s_sleep(1);
            }
            __syncthreads();
        }
    }
}

extern "C" void kernel_launch(void* const* d_in, const int* in_sizes, int n_in,
                              void* d_out, int out_size, void* d_ws, size_t ws_size,
                              hipStream_t stream) {
    const float* X   = (const float*)d_in[0];
    const float* Wih = (const float*)d_in[1];
    const float* Whh = (const float*)d_in[2];
    const float* bih = (const float*)d_in[3];
    const float* bhh = (const float*)d_in[4];
    float* out = (float*)d_out;

    u64*   ctr  = (u64*)d_ws;                         // 128 B
    short* bufA = (short*)((char*)d_ws + 128);        // 256 KB (even-t h)
    // odd-t h buffer lives in the d_out h_last tail (512 KB region, only
    // validated after t=SS-1; fully overwritten with f32 h_last at t=SS-1,
    // ordered by the step-(SS-2) barrier).
    short* bufB = (short*)(out + (size_t)BB * SS * HID);

    hipMemsetAsync(d_ws, 0, 128, stream);             // zero barrier counter

    void* args[] = { (void*)&X, (void*)&Wih, (void*)&Whh, (void*)&bih,
                     (void*)&bhh, (void*)&out, (void*)&bufA, (void*)&bufB,
                     (void*)&ctr };
    hipLaunchCooperativeKernel((const void*)gru_persistent,
                               dim3(NBLK), dim3(128), args, 0, stream);
}

// Round 5
// 5040.848 us; speedup vs baseline: 2.6851x; 1.3482x over previous
//
#include <hip/hip_runtime.h>
#include <hip/hip_bf16.h>

// Problem constants
#define BB   128
#define SS   512
#define IND  512
#define HID  1024
#define NBLK 256   // 4 row-quarters (mi) x 64 column-groups (jg)
#define NCTR 32    // barrier stripes (one 64B LLC line each)

#define WHH_LD (HID + 8)   // LDS row pad
#define WIH_LD (IND + 8)

typedef __attribute__((ext_vector_type(8))) short s8v;   // 8 x bf16
typedef __attribute__((ext_vector_type(4))) float f4v;   // MFMA accumulator
typedef unsigned long long u64;
typedef unsigned int u32;

__device__ __forceinline__ short f2bf(float f) {
    union { float f; u32 u; } v; v.f = f;
    u32 u = v.u + 0x7FFFu + ((v.u >> 16) & 1u);          // RNE
    return (short)(u >> 16);
}

// h ping-pong layout (bf16, per buffer 256 KB):
//   [wg=8][kk=32][kg=4][row 16][8 shorts]
// Reader wave (row-group wg) at iter kk: lane (n,kg) reads 16B at
// lane*16 -> perfectly lane-contiguous 1KB per instruction.
// Element (b, j) lives at byte:
//   (b/16)*32768 + (j>>5)*1024 + ((j>>3)&3)*256 + (b%16)*16 + (j&7)*2

__global__ void __launch_bounds__(128, 1)
gru_persistent(const float* __restrict__ X,     // [B,S,IND]
               const float* __restrict__ Wih,   // [3H, IND]
               const float* __restrict__ Whh,   // [3H, HID]
               const float* __restrict__ bih,   // [3H]
               const float* __restrict__ bhh,   // [3H]
               float* __restrict__ out,         // [B,S,H] ++ [B,H]
               short* __restrict__ bufA,        // ws scratch (even t)
               short* __restrict__ bufB,        // d_out tail region (odd t)
               u64*   __restrict__ ctr)         // 32 stripes, 64B apart
{
    __shared__ __align__(16) short whh_lds[48 * WHH_LD];
    __shared__ __align__(16) short wih_lds[48 * WIH_LD];

    const int tid  = threadIdx.x;
    const int wave = tid >> 6;      // 0..1
    const int lane = tid & 63;
    const int blk  = blockIdx.x;
    const int mi   = blk >> 6;      // 0..3 row quarter
    const int jg   = blk & 63;      // column group

    // ---- stage weight slices to LDS as bf16 (once) ----
    for (int idx = tid; idx < 48 * (HID / 4); idx += 128) {
        int s = idx / (HID / 4), k4 = idx % (HID / 4);
        int grow = (s >> 4) * HID + jg * 16 + (s & 15);
        float4 v = *(const float4*)(Whh + (size_t)grow * HID + k4 * 4);
        short* d = &whh_lds[s * WHH_LD + k4 * 4];
        d[0] = f2bf(v.x); d[1] = f2bf(v.y); d[2] = f2bf(v.z); d[3] = f2bf(v.w);
    }
    for (int idx = tid; idx < 48 * (IND / 4); idx += 128) {
        int s = idx / (IND / 4), k4 = idx % (IND / 4);
        int grow = (s >> 4) * HID + jg * 16 + (s & 15);
        float4 v = *(const float4*)(Wih + (size_t)grow * IND + k4 * 4);
        short* d = &wih_lds[s * WIH_LD + k4 * 4];
        d[0] = f2bf(v.x); d[1] = f2bf(v.y); d[2] = f2bf(v.z); d[3] = f2bf(v.w);
    }

    const int n  = lane & 15;
    const int kg = lane >> 4;
    const int j  = jg * 16 + n;
    const float bir = bih[j], biz = bih[HID + j], bin_ = bih[2 * HID + j];
    const float bhr = bhh[j], bhz = bhh[HID + j], bhn  = bhh[2 * HID + j];

    const int rowbase = mi * 32 + wave * 16;
    const int wg      = mi * 2 + wave;          // row-group = rowbase/16

    // writer byte offset (even lanes store packed u32 covering cols j, j+1)
    const int wkk = j >> 5, wkg = (j >> 3) & 3;
    const u32 wbyte = (u32)wg * 32768u + (u32)wkk * 1024u + (u32)wkg * 256u
                    + (u32)kg * 64u + ((u32)(n & 7) << 1);

    float hkeep[4] = {0.f, 0.f, 0.f, 0.f};      // this lane's own h elements

    __syncthreads();

    for (int t = 0; t < SS; ++t) {
        f4v acc_r  = {0.f,0.f,0.f,0.f};
        f4v acc_z  = {0.f,0.f,0.f,0.f};
        f4v acc_in = {0.f,0.f,0.f,0.f};
        f4v acc_hn = {0.f,0.f,0.f,0.f};

        // ---- gi: X[:,t,:] @ Wih_slice^T (K=512), normal cached loads ----
        {
            const float* xrow = X + ((size_t)(rowbase + n) * SS + t) * IND;
            #pragma unroll 4
            for (int kk = 0; kk < IND / 32; ++kk) {
                const int k0 = kk * 32 + kg * 8;
                const float4* px = (const float4*)(xrow + k0);
                float4 x0 = px[0], x1 = px[1];
                s8v a;
                a[0]=f2bf(x0.x); a[1]=f2bf(x0.y); a[2]=f2bf(x0.z); a[3]=f2bf(x0.w);
                a[4]=f2bf(x1.x); a[5]=f2bf(x1.y); a[6]=f2bf(x1.z); a[7]=f2bf(x1.w);
                s8v br = *(const s8v*)&wih_lds[(0 * 16 + n) * WIH_LD + k0];
                s8v bz = *(const s8v*)&wih_lds[(1 * 16 + n) * WIH_LD + k0];
                s8v bn = *(const s8v*)&wih_lds[(2 * 16 + n) * WIH_LD + k0];
                acc_r  = __builtin_amdgcn_mfma_f32_16x16x32_bf16(a, br, acc_r,  0,0,0);
                acc_z  = __builtin_amdgcn_mfma_f32_16x16x32_bf16(a, bz, acc_z,  0,0,0);
                acc_in = __builtin_amdgcn_mfma_f32_16x16x32_bf16(a, bn, acc_in, 0,0,0);
            }
        }

        // ---- gh: h_{t-1} @ Whh_slice^T (K=1024) via LLC-coherent loads ----
        if (t > 0) {
            const short* hr = (t & 1) ? bufA : bufB;          // h_{t-1}
            const u64* hb = (const u64*)hr + (size_t)wg * 4096 + lane * 2;
            s8v areg[32];
            #pragma unroll
            for (int kk = 0; kk < 32; ++kk) {
                u64 lo = __hip_atomic_load(hb + kk * 128,
                                           __ATOMIC_RELAXED, __HIP_MEMORY_SCOPE_AGENT);
                u64 hi = __hip_atomic_load(hb + kk * 128 + 1,
                                           __ATOMIC_RELAXED, __HIP_MEMORY_SCOPE_AGENT);
                union { u64 q[2]; s8v v; } u; u.q[0] = lo; u.q[1] = hi;
                areg[kk] = u.v;
            }
            #pragma unroll
            for (int kk = 0; kk < 32; ++kk) {
                const int k0 = kk * 32 + kg * 8;
                s8v br = *(const s8v*)&whh_lds[(0 * 16 + n) * WHH_LD + k0];
                s8v bz = *(const s8v*)&whh_lds[(1 * 16 + n) * WHH_LD + k0];
                s8v bn = *(const s8v*)&whh_lds[(2 * 16 + n) * WHH_LD + k0];
                acc_r  = __builtin_amdgcn_mfma_f32_16x16x32_bf16(areg[kk], br, acc_r,  0,0,0);
                acc_z  = __builtin_amdgcn_mfma_f32_16x16x32_bf16(areg[kk], bz, acc_z,  0,0,0);
                acc_hn = __builtin_amdgcn_mfma_f32_16x16x32_bf16(areg[kk], bn, acc_hn, 0,0,0);
            }
        }

        // ---- gates + state update; h kept in regs ----
        short* hw = (t & 1) ? bufB : bufA;                    // h_t
        u32 packv[4];
        #pragma unroll
        for (int r = 0; r < 4; ++r) {
            const int b = rowbase + kg * 4 + r;
            float gr = acc_r[r] + bir + bhr;
            float gz = acc_z[r] + biz + bhz;
            float rr = 1.f / (1.f + __expf(-gr));
            float zz = 1.f / (1.f + __expf(-gz));
            float hn = acc_hn[r] + bhn;                       // t=0: == bhn
            float na = acc_in[r] + bin_ + rr * hn;
            float e2 = __expf(2.f * na);
            float nn = (e2 - 1.f) / (e2 + 1.f);
            float hnew = (1.f - zz) * nn + zz * hkeep[r];
            hkeep[r] = hnew;
            out[(size_t)b * (SS * HID) + (size_t)t * HID + j] = hnew;
            if (t == SS - 1)
                out[(size_t)BB * SS * HID + (size_t)b * HID + j] = hnew;
            u32 hb16  = (u32)(unsigned short)f2bf(hnew);
            u32 other = (u32)__shfl_xor((int)hb16, 1);
            packv[r] = hb16 | (other << 16);                  // cols j (lo), j+1 (hi)
        }

        if (t < SS - 1) {
            if (!(n & 1)) {
                #pragma unroll
                for (int r = 0; r < 4; ++r)
                    __hip_atomic_store((u32*)((char*)hw + wbyte + r * 16), packv[r],
                                       __ATOMIC_RELAXED, __HIP_MEMORY_SCOPE_AGENT);
            }
            // ---- lightweight grid barrier, striped fan-in (32 LLC lines).
            // __syncthreads drains vmcnt(0) -> all sc-coherent stores are at LLC
            // before the leader's arrive-add; readers use LLC-coherent loads.
            __syncthreads();
            if (tid == 0) {
                __hip_atomic_fetch_add(&ctr[(blk & 31) * 8], 1ull,
                                       __ATOMIC_RELAXED, __HIP_MEMORY_SCOPE_AGENT);
                const u64 target = (u64)NBLK * (u64)(t + 1);
                for (;;) {
                    u64 s = 0;
                    #pragma unroll
                    for (int i = 0; i < NCTR; ++i)
                        s += __hip_atomic_load(&ctr[i * 8], __ATOMIC_RELAXED,
                                               __HIP_MEMORY_SCOPE_AGENT);
                    if (s >= target) break;
                    __builtin_amdgcn_s_sleep(1);
                }
            }
            __syncthreads();
        }
    }
}

extern "C" void kernel_launch(void* const* d_in, const int* in_sizes, int n_in,
                              void* d_out, int out_size, void* d_ws, size_t ws_size,
                              hipStream_t stream) {
    const float* X   = (const float*)d_in[0];
    const float* Wih = (const float*)d_in[1];
    const float* Whh = (const float*)d_in[2];
    const float* bih = (const float*)d_in[3];
    const float* bhh = (const float*)d_in[4];
    float* out = (float*)d_out;

    u64*   ctr  = (u64*)d_ws;                         // 32 x u64 on 64B stride = 2 KB
    short* bufA = (short*)((char*)d_ws + 2048);       // 256 KB (even-t h)
    // odd-t h buffer lives in the d_out h_last tail (512 KB region, only
    // validated after t=SS-1; fully overwritten with f32 h_last at t=SS-1,
    // ordered by the step-(SS-2) barrier).
    short* bufB = (short*)(out + (size_t)BB * SS * HID);

    hipMemsetAsync(d_ws, 0, 2048, stream);            // zero barrier stripes

    void* args[] = { (void*)&X, (void*)&Wih, (void*)&Whh, (void*)&bih,
                     (void*)&bhh, (void*)&out, (void*)&bufA, (void*)&bufB,
                     (void*)&ctr };
    hipLaunchCooperativeKernel((const void*)gru_persistent,
                               dim3(NBLK), dim3(128), args, 0, stream);
}